// Round 4
// baseline (334.387 us; speedup 1.0000x reference)
//
#include <hip/hip_runtime.h>
#include <float.h>

// Greedy dedup = masked argmax scan. B=65536 rows, S=25 steps, V=25 vocab.
//
// R1: per-thread 4B gathers -> request-bound (~110us).
// R2: global_load_lds width-4 per-step slices -> ~85us.
// R3: coalesced VGPR staging of per-step slices -> ~70us.
//   => both per-step-slice schemes stall the same way: 25 strided passes
//      (100B used per 2500B per pass) + per-step vmcnt(0)+barrier with only
//      4 waves/CU. The fix is ONE dense sequential pass.
// R4: block = 32 rows = 80,000B contiguous. Bulk-load it linearly with
//   lane-consecutive float4s (1KB/wave-instr, 16 merged line reqs) into LDS,
//   then run the whole 25-step scan from LDS (no more global reads).
//   80,000B LDS -> 2 blocks/CU resident: one block scans while the sibling
//   streams. Scan: wave 0, 2 lanes per row (vocab halves 0..12 / 12..24,
//   overlapping at 12 - harmless for max), one shfl_xor(32) combine.
//   Outputs kept in regs (s-loop fully unrolled), staged to dead LDS head,
//   copied out coalesced (each output line written exactly once).

#define S_LEN 25
#define VOCAB 25
#define ROWS 32
#define THREADS 128                       // 2 waves
#define ROW_DW (S_LEN * VOCAB)            // 625 dwords per row
#define BLK_DW (ROWS * ROW_DW)            // 20000 dwords per block
#define NV4 40                            // ceil(20000 / (4*128)) float4/thread
#define OUT_DW (ROWS * S_LEN)             // 800 dwords per output chunk

__global__ __launch_bounds__(THREADS) void greedy_dedup_kernel(
    const float* __restrict__ m, float* __restrict__ out, int B) {
  __shared__ float buf[BLK_DW];           // 80,000 B -> 2 blocks/CU

  const int t = threadIdx.x;
  const long long blk = blockIdx.x;
  const float* src = m + blk * (long long)BLK_DW;   // 16B-aligned (20000%4==0)

  // ---- Phase 1: bulk sequential load (all 128 threads) ----
  // Issue all loads first (40 float4 = 40KB in flight per wave), then commit.
  float4 v[NV4];
#pragma unroll
  for (int i = 0; i < NV4; ++i) {
    int dw = (i * THREADS + t) * 4;       // lane-consecutive float4s
    if (dw < BLK_DW) v[i] = *(const float4*)(src + dw);
  }
#pragma unroll
  for (int i = 0; i < NV4; ++i) {
    int dw = (i * THREADS + t) * 4;
    if (dw < BLK_DW) *(float4*)(&buf[dw]) = v[i];
  }
  __syncthreads();

  // ---- Phase 2: scan (wave 0 only; no barriers inside) ----
  if (t < 64) {
    const int r = t & 31;                 // row 0..31
    const int hi = t >> 5;                // 0: v 0..12, 1: v 12..24
    const int vbase = hi * 12;
    const float* myrow = &buf[r * ROW_DW];

    unsigned used = 0u;
    float acts[S_LEN], vals[S_LEN];

    float cur[13], nxt[13];
#pragma unroll
    for (int j = 0; j < 13; ++j) cur[j] = myrow[vbase + j];

#pragma unroll                           // full unroll: acts/vals stay in regs
    for (int s = 0; s < S_LEN; ++s) {
      if (s + 1 < S_LEN) {
#pragma unroll
        for (int j = 0; j < 13; ++j) nxt[j] = myrow[(s + 1) * VOCAB + vbase + j];
      }

      // Masked argmax over this half's 13 candidates. Ascending + strict '>'
      // == jnp.argmax first-max tie-breaking within the half.
      float best = -FLT_MAX;
      int bi = VOCAB;                     // sentinel: "no free candidate here"
#pragma unroll
      for (int j = 0; j < 13; ++j) {
        int vv = vbase + j;
        bool free_v = ((used >> vv) & 1u) == 0u;
        if (free_v && cur[j] > best) { best = cur[j]; bi = vv; }
      }

      // Combine halves: strictly greater wins; tie -> lower index wins.
      float obest = __shfl_xor(best, 32);
      int obi = __shfl_xor(bi, 32);
      if (obest > best || (obest == best && obi < bi)) { best = obest; bi = obi; }

      used |= (1u << bi);
      acts[s] = (float)bi;                // exact small int in fp32
      vals[s] = best;                     // original (unmasked) score

#pragma unroll
      for (int j = 0; j < 13; ++j) cur[j] = nxt[j];
    }

    // Stage outputs over the (now dead) head of buf: [act 800][val 800].
    if (t < 32) {
#pragma unroll
      for (int s = 0; s < S_LEN; ++s) {
        buf[r * S_LEN + s] = acts[s];
        buf[OUT_DW + r * S_LEN + s] = vals[s];
      }
    }
  }
  __syncthreads();

  // ---- Phase 3: coalesced copy-out (contiguous 800-dword chunks) ----
  float* gact = out + blk * OUT_DW;
  float* gval = out + (long long)B * S_LEN + blk * OUT_DW;
  for (int idx = t; idx < OUT_DW; idx += THREADS) {
    gact[idx] = buf[idx];
    gval[idx] = buf[OUT_DW + idx];
  }
}

extern "C" void kernel_launch(void* const* d_in, const int* in_sizes, int n_in,
                              void* d_out, int out_size, void* d_ws, size_t ws_size,
                              hipStream_t stream) {
  const float* m = (const float*)d_in[0];
  float* out = (float*)d_out;
  int B = in_sizes[0] / ROW_DW;           // 65536
  int grid = B / ROWS;                    // 2048 blocks
  greedy_dedup_kernel<<<grid, THREADS, 0, stream>>>(m, out, B);
}

// Round 5
// 259.423 us; speedup vs baseline: 1.2890x; 1.2890x over previous
//
#include <hip/hip_runtime.h>
#include <float.h>

// Greedy dedup = masked argmax scan. B=65536 rows, S=25 steps, V=25 vocab.
//
// R1: per-thread 4B gathers -> request-bound (~110us kernel).
// R2: global_load_lds width=4 per-step slices -> ~85us.
// R3: coalesced VGPR staging of per-step slices -> ~77us (25 strided passes
//     is structurally bad; one dense pass is the fix).
// R4: dense pass, but float4 v[40] staging spilled to scratch (VGPR 132 vs
//     160 needed): WRITE_SIZE 172.8MB = 160MB spill + 12.8MB out -> 178us.
//     FETCH 160.5MB == ideal, so the dense-pass structure is right.
// R5: dense pass via global_load_lds WIDTH=16 (m97-verified fast DMA path;
//     zero VGPRs, no spill possible). Block = 16 rows = 1 wave = 40,000B LDS
//     -> 4 resident blocks/CU (load/scan staggering, no inter-wave coupling).
//     Scan: 4 lanes/row, overlapping 7-wide vocab spans {0,6,12,18}+0..6
//     (overlap harmless for max), two shfl_xor combines. Outputs in regs
//     (s-loop fully unrolled), staged to dead LDS head, coalesced copy-out.

#define S_LEN 25
#define VOCAB 25
#define ROWS 16
#define THREADS 64                         // 1 wave
#define ROW_DW (S_LEN * VOCAB)             // 625 dwords per row
#define BLK_DW (ROWS * ROW_DW)             // 10000 dwords = 40,000 B
#define OUT_DW (ROWS * S_LEN)              // 400 dwords per output chunk
#define DMA_FULL (BLK_DW / 256)            // 39 full wave-wide 16B DMAs
#define TAIL_DW (BLK_DW - DMA_FULL * 256)  // 16 leftover dwords

__device__ __forceinline__ void gld16(const float* g, float* l) {
  // async global->LDS DMA, 16B/lane; LDS dest = wave-uniform base + lane*16
  __builtin_amdgcn_global_load_lds(
      (const __attribute__((address_space(1))) void*)g,
      (__attribute__((address_space(3))) void*)l, 16, 0, 0);
}

__global__ __launch_bounds__(THREADS) void greedy_dedup_kernel(
    const float* __restrict__ m, float* __restrict__ out, int B) {
  __shared__ __align__(16) float buf[BLK_DW];   // 40,000 B -> 4 blocks/CU

  const int t = threadIdx.x;                    // 0..63 == lane
  const long long blk = blockIdx.x;
  const float* src = m + blk * (long long)BLK_DW;  // 16B-aligned (40000%16==0)

  // ---- Phase 1: dense sequential DMA, all 39 issues in flight ----
#pragma unroll
  for (int k = 0; k < DMA_FULL; ++k)
    gld16(src + k * 256 + t * 4, &buf[k * 256]);   // 1KB contiguous per issue
  if (t < TAIL_DW)
    buf[DMA_FULL * 256 + t] = src[DMA_FULL * 256 + t];
  __syncthreads();   // drains vmcnt (DMA) + lgkmcnt before LDS reads

  // ---- Phase 2: 25-step scan, 4 lanes/row ----
  const int row = t & 15;
  const int h = t >> 4;                   // 0..3
  const int vb = h * 6;                   // spans 0-6,6-12,12-18,18-24
  const float* myrow = &buf[row * ROW_DW];

  unsigned used = 0u;
  float acts[S_LEN], vals[S_LEN];
  float cur[7], nxt[7];
#pragma unroll
  for (int j = 0; j < 7; ++j) cur[j] = myrow[vb + j];

#pragma unroll                            // full unroll: acts/vals stay in regs
  for (int s = 0; s < S_LEN; ++s) {
    if (s + 1 < S_LEN) {
#pragma unroll
      for (int j = 0; j < 7; ++j) nxt[j] = myrow[(s + 1) * VOCAB + vb + j];
    }

    // Masked argmax over this span's 7 candidates. Ascending + strict '>'
    // == jnp.argmax first-max tie-breaking.
    float best = -FLT_MAX;
    int bi = 31;                          // sentinel (can never win: scores
                                          // are finite normals > -FLT_MAX)
#pragma unroll
    for (int j = 0; j < 7; ++j) {
      int vv = vb + j;
      bool fr = ((used >> vv) & 1u) == 0u;
      if (fr && cur[j] > best) { best = cur[j]; bi = vv; }
    }

    // Combine 4 lanes of this row: greater wins; tie -> lower index.
    float ob = __shfl_xor(best, 16); int oi = __shfl_xor(bi, 16);
    if (ob > best || (ob == best && oi < bi)) { best = ob; bi = oi; }
    ob = __shfl_xor(best, 32); oi = __shfl_xor(bi, 32);
    if (ob > best || (ob == best && oi < bi)) { best = ob; bi = oi; }

    used |= (1u << bi);
    acts[s] = (float)bi;                  // exact small int in fp32
    vals[s] = best;                       // original (unmasked) score

#pragma unroll
    for (int j = 0; j < 7; ++j) cur[j] = nxt[j];
  }

  // ---- Phase 3: stage outputs over dead LDS head, coalesced copy-out ----
  if (h == 0) {
#pragma unroll
    for (int s = 0; s < S_LEN; ++s) {
      buf[row * S_LEN + s] = acts[s];              // [0..399]   actions
      buf[OUT_DW + row * S_LEN + s] = vals[s];     // [400..799] scores
    }
  }
  __syncthreads();   // cross-lane LDS visibility (single wave: near-free)

  float* gact = out + blk * OUT_DW;
  float* gval = out + (long long)B * S_LEN + blk * OUT_DW;
#pragma unroll
  for (int k = 0; k < 7; ++k) {
    int idx = k * 64 + t;
    if (idx < OUT_DW) {
      gact[idx] = buf[idx];
      gval[idx] = buf[OUT_DW + idx];
    }
  }
}

extern "C" void kernel_launch(void* const* d_in, const int* in_sizes, int n_in,
                              void* d_out, int out_size, void* d_ws, size_t ws_size,
                              hipStream_t stream) {
  const float* m = (const float*)d_in[0];
  float* out = (float*)d_out;
  int B = in_sizes[0] / ROW_DW;           // 65536
  int grid = B / ROWS;                    // 4096 one-wave blocks
  greedy_dedup_kernel<<<grid, THREADS, 0, stream>>>(m, out, B);
}

// Round 6
// 248.041 us; speedup vs baseline: 1.3481x; 1.0459x over previous
//
#include <hip/hip_runtime.h>
#include <float.h>

// Greedy dedup = masked argmax scan. B=65536 rows, S=25 steps, V=25 vocab.
//
// R1: per-thread 4B gathers -> request-bound, ~110us.
// R2: global_load_lds width=4, per-step slices -> ~82us.
// R3: plain coalesced loads, per-step slices -> ~70us (best so far).
// R4: dense pass, float4 v[40] staging -> scratch spill (160MB extra WRITE),
//     178us; but FETCH == ideal -> dense-pass structure validated.
// R5: dense pass via 39x global_load_lds width=16 -> 97.7us, VALUBusy 9%,
//     WRITE ideal. ~50k stall cycles/block unaccounted -> theory: the LDS-DMA
//     path does NOT deep-pipeline per wave (issues space at ~memory latency);
//     every DMA-heavy round (R2, R5) is slow, the plain-load round (R3) fast.
// R6: dense pass with PLAIN float4 loads -> rotating 8-reg buffer ->
//     ds_write_b128 (vmem queue pipelines 63-deep; 32 staging VGPRs, no
//     spill). Block = 8 rows = 1 wave = 20,000B LDS -> 8 blocks/CU resident
//     = 2 waves/SIMD (2x latency hiding in both phases). Scan: 8 lanes/row,
//     4-wide spans vb=3h (overlap harmless for max), 3-hop shfl_xor
//     butterfly; acts/vals in regs (s-loop fully unrolled), staged to dead
//     LDS head, coalesced copy-out.

#define S_LEN 25
#define VOCAB 25
#define ROWS 8
#define THREADS 64                       // 1 wave
#define ROW_DW (S_LEN * VOCAB)           // 625 dwords per row
#define BLK_DW (ROWS * ROW_DW)           // 5000 dwords = 20,000 B
#define BLK_V4 (BLK_DW / 4)              // 1250 float4 per block
#define FULL_ROUNDS (BLK_V4 / 64)        // 19 full wave-wide rounds
#define TAIL_V4 (BLK_V4 - FULL_ROUNDS * 64)  // 34 leftover float4
#define OUT_DW (ROWS * S_LEN)            // 200 dwords per output chunk
#define DEPTH 8                          // rotating staging regs (32 VGPRs)

__global__ __launch_bounds__(THREADS) void greedy_dedup_kernel(
    const float* __restrict__ m, float* __restrict__ out, int B) {
  __shared__ __align__(16) float buf[BLK_DW];   // 20,000 B -> 8 blocks/CU

  const int t = threadIdx.x;                    // 0..63 == lane
  const long long blk = blockIdx.x;
  const float4* src4 = (const float4*)(m + blk * (long long)BLK_DW); // 16B ok
  float4* buf4 = (float4*)buf;

  // ---- Phase 1: dense sequential load, rotating 8-deep pipeline ----
  float4 reg[DEPTH];
#pragma unroll
  for (int k = 0; k < DEPTH; ++k) reg[k] = src4[k * 64 + t];
#pragma unroll
  for (int k = 0; k < FULL_ROUNDS; ++k) {
    float4 v = reg[k & (DEPTH - 1)];            // waits vmcnt for this slot
    if (k + DEPTH < FULL_ROUNDS)
      reg[k & (DEPTH - 1)] = src4[(k + DEPTH) * 64 + t];
    buf4[k * 64 + t] = v;                       // ds_write_b128, linear layout
  }
  if (t < TAIL_V4) buf4[FULL_ROUNDS * 64 + t] = src4[FULL_ROUNDS * 64 + t];
  __syncthreads();

  // ---- Phase 2: 25-step scan, 8 lanes/row, 4-wide spans ----
  const int row = t & 7;
  const int h = t >> 3;                   // 0..7
  const int vb = h * 3;                   // spans {0..3},{3..6},...,{21..24}
  const float* myrow = &buf[row * ROW_DW];

  unsigned used = 0u;
  float acts[S_LEN], vals[S_LEN];
  float cur[4], nxt[4];
#pragma unroll
  for (int j = 0; j < 4; ++j) cur[j] = myrow[vb + j];

#pragma unroll                            // full unroll: acts/vals stay in regs
  for (int s = 0; s < S_LEN; ++s) {
    if (s + 1 < S_LEN) {
#pragma unroll
      for (int j = 0; j < 4; ++j) nxt[j] = myrow[(s + 1) * VOCAB + vb + j];
    }

    // Masked argmax over this span's 4 candidates. Ascending + strict '>'
    // == jnp.argmax first-max tie-breaking.
    float best = -FLT_MAX;
    int bi = 31;                          // sentinel: loses to any real score
#pragma unroll
    for (int j = 0; j < 4; ++j) {
      int vv = vb + j;
      bool fr = ((used >> vv) & 1u) == 0u;
      if (fr && cur[j] > best) { best = cur[j]; bi = vv; }
    }

    // Butterfly over the row's 8 lanes (xor 8,16,32): greater wins; tie ->
    // lower index wins (overlapping spans agree on duplicated indices).
#pragma unroll
    for (int d = 8; d <= 32; d <<= 1) {
      float ob = __shfl_xor(best, d);
      int oi = __shfl_xor(bi, d);
      if (ob > best || (ob == best && oi < bi)) { best = ob; bi = oi; }
    }

    used |= (1u << bi);
    acts[s] = (float)bi;                  // exact small int in fp32
    vals[s] = best;                       // original (unmasked) score

#pragma unroll
    for (int j = 0; j < 4; ++j) cur[j] = nxt[j];
  }

  // ---- Phase 3: stage outputs over dead LDS head, coalesced copy-out ----
  if (h == 0) {                           // t == row, one lane per row
#pragma unroll
    for (int s = 0; s < S_LEN; ++s) {
      buf[row * S_LEN + s] = acts[s];             // [0..199]   actions
      buf[OUT_DW + row * S_LEN + s] = vals[s];    // [200..399] scores
    }
  }
  __syncthreads();

  float* gact = out + blk * OUT_DW;
  float* gval = out + (long long)B * S_LEN + blk * OUT_DW;
#pragma unroll
  for (int k = 0; k < 4; ++k) {
    int idx = k * 64 + t;
    if (idx < OUT_DW) {
      gact[idx] = buf[idx];
      gval[idx] = buf[OUT_DW + idx];
    }
  }
}

extern "C" void kernel_launch(void* const* d_in, const int* in_sizes, int n_in,
                              void* d_out, int out_size, void* d_ws, size_t ws_size,
                              hipStream_t stream) {
  const float* m = (const float*)d_in[0];
  float* out = (float*)d_out;
  int B = in_sizes[0] / ROW_DW;           // 65536
  int grid = B / ROWS;                    // 8192 one-wave blocks
  greedy_dedup_kernel<<<grid, THREADS, 0, stream>>>(m, out, B);
}